// Round 9
// baseline (295.136 us; speedup 1.0000x reference)
//
#include <hip/hip_runtime.h>

// Decoder scan: B=256 batch, T=128, M=64, P=64, 127 sequential steps.
// One block per batch element (256 blocks = 256 CUs), 512 threads (8 waves,
// 2 waves/SIMD for TLP). ONE barrier per step. Every wave redundantly
// computes the LSTM gates AND the full dproj matvec: h,c go to a
// wave-private LDS buffer, read back as uniform-address ds_read_b128
// broadcasts (LDS pipe, not VALU), FMA'd against wd_r[128] registers.
// dproj bounces through wave-private LDS; each wave computes 16 attention
// scores (its own t's) from register-resident Ue, and publishes 2 scalars
// (unscaled ctx.Wde numerator + softmax denom) per step, parity
// double-buffered. Softmax division deferred to next step's phase a.

#define Bn 256
#define Tn 128
#define Mn 64
#define Pn 64
#define NTH 512
#define NW 8
#define UST 68    // padded stride (floats) for enc_s / Ud_s (init staging)
#define DPST 72   // stride for wave-private dproj copies (16B aligned)
#define HCST 132  // stride for wave-private hc copies (16B aligned)
#define K2C 2.885390081777927f  // 2 * log2(e)

typedef float f32x2 __attribute__((ext_vector_type(2)));

__device__ __forceinline__ float fexp(float x) {   // e^x
    return __builtin_amdgcn_exp2f(x * 1.44269504088896341f);
}
__device__ __forceinline__ float fexp2(float x) { return __builtin_amdgcn_exp2f(x); }
__device__ __forceinline__ float frcp(float x) { return __builtin_amdgcn_rcpf(x); }
__device__ __forceinline__ float fsig(float x) { return frcp(1.0f + fexp(-x)); }
__device__ __forceinline__ float ftanh(float x) { return 1.0f - 2.0f * frcp(1.0f + fexp(2.0f * x)); }

template <int CTRL>
__device__ __forceinline__ float dppmov(float x) {
    // invalid source lanes contribute old=0 (safe for additive reductions)
    return __int_as_float(__builtin_amdgcn_update_dpp(
        0, __float_as_int(x), CTRL, 0xf, 0xf, false));
}
__device__ __forceinline__ float rdlane(float x, int l) {
    return __int_as_float(__builtin_amdgcn_readlane(__float_as_int(x), l));
}
// 64-lane sum; total lands in lane 63 (NOT broadcast)
__device__ __forceinline__ float wavesum63(float x) {
    x += dppmov<0x111>(x);  // row_shr:1
    x += dppmov<0x112>(x);  // row_shr:2
    x += dppmov<0x114>(x);  // row_shr:4
    x += dppmov<0x118>(x);  // row_shr:8
    x += dppmov<0x142>(x);  // row_bcast:15
    x += dppmov<0x143>(x);  // row_bcast:31
    return x;
}

// LDS layout (floats):
#define OFF_ENC   0        // 128*68 = 8704 (init only)
#define OFF_UD    8704     // 64*68  = 4352 (init only)
#define OFF_PRE   13056    // 256 (init only)
#define OFF_DPW   13312    // 8*72 = 576 (wave-private dproj)
#define OFF_HC    13888    // 8*132 = 1056 (wave-private h,c)
#define OFF_YSDEN 14944    // f32x2[2][8] = 32 floats (8B aligned)
#define OFF_CTXP  14976    // 512
#define SMEM_FLOATS 15488  // 62.0 KB

__global__ __launch_bounds__(NTH, 2)
void decoder_kernel(const float* __restrict__ data, const float* __restrict__ enc,
                    const float* __restrict__ h0, const float* __restrict__ s0,
                    const float* __restrict__ W_dense, const float* __restrict__ b_dense,
                    const float* __restrict__ Wk, const float* __restrict__ Uk,
                    const float* __restrict__ bk,
                    const float* __restrict__ Wd, const float* __restrict__ bWd,
                    const float* __restrict__ Ud, const float* __restrict__ bUd,
                    const float* __restrict__ vd, const float* __restrict__ bvd,
                    const float* __restrict__ Wvb, const float* __restrict__ bvb,
                    const float* __restrict__ Wb, const float* __restrict__ bWb,
                    float* __restrict__ out)
{
    extern __shared__ float smem[];
    float* enc_s  = smem + OFF_ENC;
    float* Ud_s   = smem + OFF_UD;
    float* pre_s  = smem + OFF_PRE;
    float* dprojw = smem + OFF_DPW;
    float* hcw    = smem + OFF_HC;
    f32x2* ysden  = (f32x2*)(smem + OFF_YSDEN);
    float* ctxp   = smem + OFF_CTXP;

    const int b    = blockIdx.x;
    const int tid  = threadIdx.x;
    const int lane = tid & 63;
    const int wv   = tid >> 6;          // 0..7

    // ---- init: stage enc (stride 68), Ud (stride 68); pre = h0@Uk+bk ----
    {
        const float* encg = enc + (size_t)b * Tn * Mn;
        #pragma unroll
        for (int i = 0; i < 4; i++) {
            int flat = (i * NTH + tid) * 4;          // 0..8188
            int t = flat >> 6, m = flat & 63;
            *(float4*)(enc_s + t * UST + m) = *(const float4*)(encg + flat);
        }
        #pragma unroll
        for (int i = 0; i < 2; i++) {
            int flat = (i * NTH + tid) * 4;          // 0..4092
            int k = flat >> 6, n = flat & 63;
            *(float4*)(Ud_s + k * UST + n) = *(const float4*)(Ud + flat);
        }
        if (tid < 4 * Pn) {
            float s = bk[tid];
            const float* h0b = h0 + b * Pn;
            #pragma unroll
            for (int k = 0; k < Pn; k++) s = fmaf(h0b[k], Uk[k * 4 * Pn + tid], s);
            pre_s[tid] = s;
        }
        if (tid < 2 * NW) {                          // both parities
            f32x2 z; z.x = 0.0f; z.y = 0.125f;       // den sums to 1 -> ctx=0
            ysden[tid] = z;
        }
    }
    __syncthreads();

    // ---- Ue slice in registers: ue = K2*(enc[t] @ Ud[:, m0..m0+15] + bUd)
    //      t = 16*wv + (lane>>2), q = lane&3, m0 = 16q
    const int t_e = 16 * wv + (lane >> 2), q_e = lane & 3, m0 = q_e * 16;
    f32x2 ue2[8];
    {
        float acc[16];
        #pragma unroll
        for (int j = 0; j < 16; j++) acc[j] = bUd[m0 + j];
        for (int k = 0; k < Mn; k++) {
            float a = enc_s[t_e * UST + k];
            const float4* ud = (const float4*)(Ud_s + k * UST + m0);
            #pragma unroll
            for (int j4 = 0; j4 < 4; j4++) {
                float4 u = ud[j4];
                acc[4 * j4 + 0] = fmaf(a, u.x, acc[4 * j4 + 0]);
                acc[4 * j4 + 1] = fmaf(a, u.y, acc[4 * j4 + 1]);
                acc[4 * j4 + 2] = fmaf(a, u.z, acc[4 * j4 + 2]);
                acc[4 * j4 + 3] = fmaf(a, u.w, acc[4 * j4 + 3]);
            }
        }
        #pragma unroll
        for (int j = 0; j < 8; j++) {
            ue2[j].x = K2C * acc[2 * j];
            ue2[j].y = K2C * acc[2 * j + 1];
        }
    }

    // ---- per-lane loop-invariant registers ----
    float enc_r[16];                                   // wave's 16 enc rows
    #pragma unroll
    for (int j = 0; j < 16; j++)
        enc_r[j] = enc_s[(16 * wv + j) * UST + lane];
    float wd_r[128];                                   // FULL K2*Wd column m=lane
    #pragma unroll
    for (int k = 0; k < 128; k++)
        wd_r[k] = K2C * Wd[k * Mn + lane];
    const float W0  = W_dense[0];
    const float bd  = b_dense[0];
    const float Wde = W_dense[1 + lane];
    const float wk_i = Wk[lane], wk_f = Wk[64 + lane],
                wk_g = Wk[128 + lane], wk_o = Wk[192 + lane];
    const float s0v   = s0[b * Pn + lane];
    const float bvd0  = bvd[0];
    const float bwd_l = K2C * bWd[lane];
    f32x2 vd2[8];
    float sumvd16 = 0.0f;
    #pragma unroll
    for (int j = 0; j < 8; j++) {
        float va = vd[m0 + 2 * j], vb = vd[m0 + 2 * j + 1];
        vd2[j].x = -2.0f * va; vd2[j].y = -2.0f * vb;
        sumvd16 += va + vb;
    }
    const float pre_i = pre_s[lane];
    const float pre_f = pre_s[64 + lane];
    const float pre_g = pre_s[128 + lane];
    const float pre_o = pre_s[192 + lane];
    // x row in registers (broadcast later via v_readlane)
    const float* xb = data + (size_t)b * (Tn - 1);
    const float x_lo = xb[lane];                           // 0..63
    const float x_hi = (lane < 63) ? xb[64 + lane] : 0.0f; // 64..126

    float h = 0.0f, c = 0.0f;
    float* dp_my = dprojw + wv * DPST;                 // wave-private dproj
    float* hc_my = hcw + wv * HCST;                    // wave-private h,c

    for (int st = 0; st < Tn - 1; ++st) {
        const int par = st & 1, nxt = par ^ 1;

        // phase a: y = x[st]*W0 + (sum_w ysraw)/(sum_w den) + bd
        f32x2 yv = ysden[par * NW + (lane & 7)];
        yv.x += dppmov<0x111>(yv.x); yv.y += dppmov<0x111>(yv.y);
        yv.x += dppmov<0x112>(yv.x); yv.y += dppmov<0x112>(yv.y);
        yv.x += dppmov<0x114>(yv.x); yv.y += dppmov<0x114>(yv.y);
        float ytot = rdlane(yv.x, 7);
        float dtot = rdlane(yv.y, 7);
        float xs = (st < 64) ? rdlane(x_lo, st) : rdlane(x_hi, st - 64);
        float y = fmaf(xs, W0, fmaf(ytot, frcp(dtot), bd));

        // phase b: LSTM gates (state resets to h0,s0; pre = h0@Uk+bk)
        float zi = fmaf(y, wk_i, pre_i);
        float zf = fmaf(y, wk_f, pre_f);
        float zg = fmaf(y, wk_g, pre_g);
        float zo = fmaf(y, wk_o, pre_o);
        c = fsig(zf) * s0v + fsig(zi) * ftanh(zg);
        h = fsig(zo) * ftanh(c);

        // phase cd: FULL dproj[m=lane] per wave (redundant), no barrier.
        // h,c -> wave-private LDS; read back as uniform-address b128
        // broadcasts (LDS pipe), FMA against wd_r registers.
        {
            hc_my[lane] = h;
            hc_my[64 + lane] = c;
            float p0 = 0.0f, p1 = 0.0f, p2 = 0.0f, p3 = 0.0f;
            #pragma unroll
            for (int k4 = 0; k4 < 32; k4++) {
                float4 hv = *(const float4*)(hc_my + 4 * k4);  // uniform addr
                p0 = fmaf(hv.x, wd_r[4 * k4 + 0], p0);
                p1 = fmaf(hv.y, wd_r[4 * k4 + 1], p1);
                p2 = fmaf(hv.z, wd_r[4 * k4 + 2], p2);
                p3 = fmaf(hv.w, wd_r[4 * k4 + 3], p3);
            }
            dp_my[lane] = ((p0 + p1) + (p2 + p3)) + bwd_l;  // pre-scaled K2
        }
        // in-wave LDS RAW: compiler inserts lgkmcnt waits; no cross-wave use.

        // phase e: e[t] = sum_m vd*tanh(dproj+Ue); ex=exp(e) at lanes 4j+3
        float ex;
        {
            float4 d[4];
            const float4* dp4 = (const float4*)(dp_my + m0);
            #pragma unroll
            for (int i = 0; i < 4; i++) d[i] = dp4[i];
            f32x2 accA; accA.x = sumvd16; accA.y = 0.0f;
            f32x2 accB; accB.x = 0.0f;    accB.y = 0.0f;
            #pragma unroll
            for (int i = 0; i < 4; i++) {
                f32x2 sA, rA, sB, rB;
                sA.x = d[i].x + ue2[2 * i].x;     sA.y = d[i].y + ue2[2 * i].y;
                rA.x = frcp(1.0f + fexp2(sA.x));  rA.y = frcp(1.0f + fexp2(sA.y));
                accA += vd2[2 * i] * rA;
                sB.x = d[i].z + ue2[2 * i + 1].x; sB.y = d[i].w + ue2[2 * i + 1].y;
                rB.x = frcp(1.0f + fexp2(sB.x));  rB.y = frcp(1.0f + fexp2(sB.y));
                accB += vd2[2 * i + 1] * rB;
            }
            f32x2 accT = accA + accB;
            float acc = accT.x + accT.y;
            acc += dppmov<0x111>(acc);
            acc += dppmov<0x112>(acc);      // lane 4j+3 holds full e[t]
            ex = fexp(acc + bvd0);          // valid at lanes 4j+3
        }

        // phase f: ctx partial (lane=m) from own-wave ex; publish 2 scalars
        {
            float p0 = 0.0f, p1 = 0.0f, p2 = 0.0f, p3 = 0.0f;
            #pragma unroll
            for (int j = 0; j < 4; j++) {
                p0 = fmaf(rdlane(ex, 4 * j + 3),        enc_r[j],      p0);
                p1 = fmaf(rdlane(ex, 4 * (j + 4) + 3),  enc_r[4 + j],  p1);
                p2 = fmaf(rdlane(ex, 4 * (j + 8) + 3),  enc_r[8 + j],  p2);
                p3 = fmaf(rdlane(ex, 4 * (j + 12) + 3), enc_r[12 + j], p3);
            }
            float ctxpart = (p0 + p1) + (p2 + p3);      // UNscaled
            if (st == Tn - 2) ctxp[wv * 64 + lane] = ctxpart;
            f32x2 w2;
            w2.x = ctxpart * Wde;
            w2.y = ((lane & 3) == 3) ? ex : 0.0f;       // denom contribution
            w2.x += dppmov<0x111>(w2.x); w2.y += dppmov<0x111>(w2.y);
            w2.x += dppmov<0x112>(w2.x); w2.y += dppmov<0x112>(w2.y);
            w2.x += dppmov<0x114>(w2.x); w2.y += dppmov<0x114>(w2.y);
            w2.x += dppmov<0x118>(w2.x); w2.y += dppmov<0x118>(w2.y);
            w2.x += dppmov<0x142>(w2.x); w2.y += dppmov<0x142>(w2.y);
            w2.x += dppmov<0x143>(w2.x); w2.y += dppmov<0x143>(w2.y);
            if (lane == 63) ysden[nxt * NW + wv] = w2;
        }
        __syncthreads();  // the ONE barrier: ysden (and last-step ctxp) ready
    }

    // ---- epilogue: out[b][p] = ((concat(h,ctx) @ Wvb + bvb) * Wb[p]) + bWb[p]
    //      last step (st=126, par=0) wrote ysden[1][*]; ctxp holds unscaled.
    if (wv == 0) {
        float dtot = 0.0f;
        #pragma unroll
        for (int w = 0; w < NW; w++) dtot += ysden[NW + w].y;
        float invS = frcp(dtot);
        float ctxm = 0.0f;
        #pragma unroll
        for (int w = 0; w < NW; w++) ctxm += ctxp[w * 64 + lane];
        ctxm *= invS;
        float part = h * Wvb[lane] + ctxm * Wvb[64 + lane];
        float v = rdlane(wavesum63(part), 63) + bvb[0];
        out[(size_t)b * Pn + lane] = fmaf(v, Wb[lane], bWb[lane]);
    }
}

extern "C" void kernel_launch(void* const* d_in, const int* in_sizes, int n_in,
                              void* d_out, int out_size, void* d_ws, size_t ws_size,
                              hipStream_t stream) {
    const float* data    = (const float*)d_in[0];
    const float* enc     = (const float*)d_in[1];
    const float* h0      = (const float*)d_in[2];
    const float* s0      = (const float*)d_in[3];
    const float* W_dense = (const float*)d_in[4];
    const float* b_dense = (const float*)d_in[5];
    const float* Wk      = (const float*)d_in[6];
    const float* Uk      = (const float*)d_in[7];
    const float* bk      = (const float*)d_in[8];
    const float* Wd      = (const float*)d_in[9];
    const float* bWd     = (const float*)d_in[10];
    const float* Ud      = (const float*)d_in[11];
    const float* bUd     = (const float*)d_in[12];
    const float* vd      = (const float*)d_in[13];
    const float* bvd     = (const float*)d_in[14];
    const float* Wvb     = (const float*)d_in[15];
    const float* bvb     = (const float*)d_in[16];
    const float* Wb      = (const float*)d_in[17];
    const float* bWb     = (const float*)d_in[18];

    decoder_kernel<<<Bn, NTH, SMEM_FLOATS * sizeof(float), stream>>>(
        data, enc, h0, s0, W_dense, b_dense, Wk, Uk, bk,
        Wd, bWd, Ud, bUd, vd, bvd, Wvb, bvb, Wb, bWb, (float*)d_out);
}

// Round 10
// 283.675 us; speedup vs baseline: 1.0404x; 1.0404x over previous
//
#include <hip/hip_runtime.h>

// Decoder scan: B=256 batch, T=128, M=64, P=64, 127 sequential steps.
// One block per batch element (256 blocks = 256 CUs), 512 threads (8 waves,
// 2/SIMD). TWO barriers per step, dproj DISTRIBUTED (16 k's per wave):
//   a: y from published scalars (parity dbuf)   [no barrier]
//   b: gates (wave-redundant, per-lane)         [no barrier]
//   c: dpart[wv][m] = 16-term partial           -> B1
//   d: every wave sums 8 partials (8x ds_read_b32) -> wave-private dproj
//   e: 16 attention scores per wave (reg Ue)    [in-wave LDS bounce only]
//   f: ctx partial + publish 2 scalars          -> B2
// Softmax division deferred to next step's phase a.

#define Bn 256
#define Tn 128
#define Mn 64
#define Pn 64
#define NTH 512
#define NW 8
#define UST 68    // padded stride (floats) for enc_s / Ud_s (init staging)
#define DPST 72   // stride for dpart rows / wave-private dproj copies
#define K2C 2.885390081777927f  // 2 * log2(e)

typedef float f32x2 __attribute__((ext_vector_type(2)));

__device__ __forceinline__ float fexp(float x) {   // e^x
    return __builtin_amdgcn_exp2f(x * 1.44269504088896341f);
}
__device__ __forceinline__ float fexp2(float x) { return __builtin_amdgcn_exp2f(x); }
__device__ __forceinline__ float frcp(float x) { return __builtin_amdgcn_rcpf(x); }
__device__ __forceinline__ float fsig(float x) { return frcp(1.0f + fexp(-x)); }
__device__ __forceinline__ float ftanh(float x) { return 1.0f - 2.0f * frcp(1.0f + fexp(2.0f * x)); }

template <int CTRL>
__device__ __forceinline__ float dppmov(float x) {
    // invalid source lanes contribute old=0 (safe for additive reductions)
    return __int_as_float(__builtin_amdgcn_update_dpp(
        0, __float_as_int(x), CTRL, 0xf, 0xf, false));
}
__device__ __forceinline__ float rdlane(float x, int l) {
    return __int_as_float(__builtin_amdgcn_readlane(__float_as_int(x), l));
}
// 64-lane sum; total lands in lane 63 (NOT broadcast)
__device__ __forceinline__ float wavesum63(float x) {
    x += dppmov<0x111>(x);  // row_shr:1
    x += dppmov<0x112>(x);  // row_shr:2
    x += dppmov<0x114>(x);  // row_shr:4
    x += dppmov<0x118>(x);  // row_shr:8
    x += dppmov<0x142>(x);  // row_bcast:15
    x += dppmov<0x143>(x);  // row_bcast:31
    return x;
}

// LDS layout (floats):
#define OFF_ENC   0        // 128*68 = 8704 (init only)
#define OFF_UD    8704     // 64*68  = 4352 (init only)
#define OFF_PRE   13056    // 256 (init only)
#define OFF_DPART 13312    // 8*72 = 576 (shared dproj partials)
#define OFF_DPW   13888    // 8*72 = 576 (wave-private dproj copies)
#define OFF_YSDEN 14464    // f32x2[2][8] = 32 floats (8B aligned)
#define OFF_CTXP  14496    // 512
#define SMEM_FLOATS 15008  // 60.0 KB

__global__ __launch_bounds__(NTH, 2)
void decoder_kernel(const float* __restrict__ data, const float* __restrict__ enc,
                    const float* __restrict__ h0, const float* __restrict__ s0,
                    const float* __restrict__ W_dense, const float* __restrict__ b_dense,
                    const float* __restrict__ Wk, const float* __restrict__ Uk,
                    const float* __restrict__ bk,
                    const float* __restrict__ Wd, const float* __restrict__ bWd,
                    const float* __restrict__ Ud, const float* __restrict__ bUd,
                    const float* __restrict__ vd, const float* __restrict__ bvd,
                    const float* __restrict__ Wvb, const float* __restrict__ bvb,
                    const float* __restrict__ Wb, const float* __restrict__ bWb,
                    float* __restrict__ out)
{
    extern __shared__ float smem[];
    float* enc_s  = smem + OFF_ENC;
    float* Ud_s   = smem + OFF_UD;
    float* pre_s  = smem + OFF_PRE;
    float* dpart  = smem + OFF_DPART;
    float* dprojw = smem + OFF_DPW;
    f32x2* ysden  = (f32x2*)(smem + OFF_YSDEN);
    float* ctxp   = smem + OFF_CTXP;

    const int b    = blockIdx.x;
    const int tid  = threadIdx.x;
    const int lane = tid & 63;
    const int wv   = tid >> 6;          // 0..7

    // ---- init: stage enc (stride 68), Ud (stride 68); pre = h0@Uk+bk ----
    {
        const float* encg = enc + (size_t)b * Tn * Mn;
        #pragma unroll
        for (int i = 0; i < 4; i++) {
            int flat = (i * NTH + tid) * 4;          // 0..8188
            int t = flat >> 6, m = flat & 63;
            *(float4*)(enc_s + t * UST + m) = *(const float4*)(encg + flat);
        }
        #pragma unroll
        for (int i = 0; i < 2; i++) {
            int flat = (i * NTH + tid) * 4;          // 0..4092
            int k = flat >> 6, n = flat & 63;
            *(float4*)(Ud_s + k * UST + n) = *(const float4*)(Ud + flat);
        }
        if (tid < 4 * Pn) {
            float s = bk[tid];
            const float* h0b = h0 + b * Pn;
            #pragma unroll
            for (int k = 0; k < Pn; k++) s = fmaf(h0b[k], Uk[k * 4 * Pn + tid], s);
            pre_s[tid] = s;
        }
        if (tid < 2 * NW) {                          // both parities
            f32x2 z; z.x = 0.0f; z.y = 0.125f;       // den sums to 1 -> ctx=0
            ysden[tid] = z;
        }
    }
    __syncthreads();

    // ---- Ue slice in registers: ue = K2*(enc[t] @ Ud[:, m0..m0+15] + bUd)
    //      t = 16*wv + (lane>>2), q = lane&3, m0 = 16q
    const int t_e = 16 * wv + (lane >> 2), q_e = lane & 3, m0 = q_e * 16;
    f32x2 ue2[8];
    {
        float acc[16];
        #pragma unroll
        for (int j = 0; j < 16; j++) acc[j] = bUd[m0 + j];
        for (int k = 0; k < Mn; k++) {
            float a = enc_s[t_e * UST + k];
            const float4* ud = (const float4*)(Ud_s + k * UST + m0);
            #pragma unroll
            for (int j4 = 0; j4 < 4; j4++) {
                float4 u = ud[j4];
                acc[4 * j4 + 0] = fmaf(a, u.x, acc[4 * j4 + 0]);
                acc[4 * j4 + 1] = fmaf(a, u.y, acc[4 * j4 + 1]);
                acc[4 * j4 + 2] = fmaf(a, u.z, acc[4 * j4 + 2]);
                acc[4 * j4 + 3] = fmaf(a, u.w, acc[4 * j4 + 3]);
            }
        }
        #pragma unroll
        for (int j = 0; j < 8; j++) {
            ue2[j].x = K2C * acc[2 * j];
            ue2[j].y = K2C * acc[2 * j + 1];
        }
    }

    // ---- per-lane loop-invariant registers ----
    float enc_r[16];                                   // wave's 16 enc rows
    #pragma unroll
    for (int j = 0; j < 16; j++)
        enc_r[j] = enc_s[(16 * wv + j) * UST + lane];
    float wd_r[16];                                    // wave's 16 Wd rows (K2-scaled)
    #pragma unroll
    for (int j = 0; j < 16; j++)
        wd_r[j] = K2C * Wd[(16 * wv + j) * Mn + lane];
    const float W0  = W_dense[0];
    const float bd  = b_dense[0];
    const float Wde = W_dense[1 + lane];
    const float wk_i = Wk[lane], wk_f = Wk[64 + lane],
                wk_g = Wk[128 + lane], wk_o = Wk[192 + lane];
    const float s0v   = s0[b * Pn + lane];
    const float bvd0  = bvd[0];
    const float bwd_l = K2C * bWd[lane];
    f32x2 vd2[8];
    float sumvd16 = 0.0f;
    #pragma unroll
    for (int j = 0; j < 8; j++) {
        float va = vd[m0 + 2 * j], vb = vd[m0 + 2 * j + 1];
        vd2[j].x = -2.0f * va; vd2[j].y = -2.0f * vb;
        sumvd16 += va + vb;
    }
    const float pre_i = pre_s[lane];
    const float pre_f = pre_s[64 + lane];
    const float pre_g = pre_s[128 + lane];
    const float pre_o = pre_s[192 + lane];
    const bool hv_sel = (wv < 4);
    const int  base16 = (wv & 3) * 16;
    // x row in registers (broadcast later via v_readlane)
    const float* xb = data + (size_t)b * (Tn - 1);
    const float x_lo = xb[lane];                           // 0..63
    const float x_hi = (lane < 63) ? xb[64 + lane] : 0.0f; // 64..126

    float h = 0.0f, c = 0.0f;
    float* dp_my = dprojw + wv * DPST;                 // wave-private dproj

    for (int st = 0; st < Tn - 1; ++st) {
        const int par = st & 1, nxt = par ^ 1;

        // phase a: y = x[st]*W0 + (sum_w ysraw)/(sum_w den) + bd
        f32x2 yv = ysden[par * NW + (lane & 7)];
        yv.x += dppmov<0x111>(yv.x); yv.y += dppmov<0x111>(yv.y);
        yv.x += dppmov<0x112>(yv.x); yv.y += dppmov<0x112>(yv.y);
        yv.x += dppmov<0x114>(yv.x); yv.y += dppmov<0x114>(yv.y);
        float ytot = rdlane(yv.x, 7);
        float dtot = rdlane(yv.y, 7);
        float xs = (st < 64) ? rdlane(x_lo, st) : rdlane(x_hi, st - 64);
        float y = fmaf(xs, W0, fmaf(ytot, frcp(dtot), bd));

        // phase b: LSTM gates (state resets to h0,s0; pre = h0@Uk+bk)
        float zi = fmaf(y, wk_i, pre_i);
        float zf = fmaf(y, wk_f, pre_f);
        float zg = fmaf(y, wk_g, pre_g);
        float zo = fmaf(y, wk_o, pre_o);
        c = fsig(zf) * s0v + fsig(zi) * ftanh(zg);
        h = fsig(zo) * ftanh(c);

        // phase c: dpart[wv][m] = sum_{j<16} hc[16wv+j] * K2*Wd[16wv+j][m]
        {
            float hv = hv_sel ? h : c;
            float p0 = 0.0f, p1 = 0.0f, p2 = 0.0f, p3 = 0.0f;
            #pragma unroll
            for (int j = 0; j < 4; j++) {
                p0 = fmaf(rdlane(hv, base16 + j),      wd_r[j],      p0);
                p1 = fmaf(rdlane(hv, base16 + 4 + j),  wd_r[4 + j],  p1);
                p2 = fmaf(rdlane(hv, base16 + 8 + j),  wd_r[8 + j],  p2);
                p3 = fmaf(rdlane(hv, base16 + 12 + j), wd_r[12 + j], p3);
            }
            dpart[wv * DPST + lane] = (p0 + p1) + (p2 + p3);
        }
        __syncthreads();  // B1: dpart ready

        // phase d: every wave (redundantly) reduces 8 partials -> wave-private
        // dproj[m=lane]; conflict-free stride-72 per-lane reads.
        {
            float v0 = dpart[0 * DPST + lane] + dpart[1 * DPST + lane];
            float v1 = dpart[2 * DPST + lane] + dpart[3 * DPST + lane];
            float v2 = dpart[4 * DPST + lane] + dpart[5 * DPST + lane];
            float v3 = dpart[6 * DPST + lane] + dpart[7 * DPST + lane];
            dp_my[lane] = ((v0 + v1) + (v2 + v3)) + bwd_l;  // pre-scaled K2
        }
        // in-wave LDS RAW below (compiler inserts lgkmcnt waits).

        // phase e: e[t] = sum_m vd*tanh(dproj+Ue); ex=exp(e) at lanes 4j+3
        float ex;
        {
            float4 d[4];
            const float4* dp4 = (const float4*)(dp_my + m0);
            #pragma unroll
            for (int i = 0; i < 4; i++) d[i] = dp4[i];
            f32x2 accA; accA.x = sumvd16; accA.y = 0.0f;
            f32x2 accB; accB.x = 0.0f;    accB.y = 0.0f;
            #pragma unroll
            for (int i = 0; i < 4; i++) {
                f32x2 sA, rA, sB, rB;
                sA.x = d[i].x + ue2[2 * i].x;     sA.y = d[i].y + ue2[2 * i].y;
                rA.x = frcp(1.0f + fexp2(sA.x));  rA.y = frcp(1.0f + fexp2(sA.y));
                accA += vd2[2 * i] * rA;
                sB.x = d[i].z + ue2[2 * i + 1].x; sB.y = d[i].w + ue2[2 * i + 1].y;
                rB.x = frcp(1.0f + fexp2(sB.x));  rB.y = frcp(1.0f + fexp2(sB.y));
                accB += vd2[2 * i + 1] * rB;
            }
            f32x2 accT = accA + accB;
            float acc = accT.x + accT.y;
            acc += dppmov<0x111>(acc);
            acc += dppmov<0x112>(acc);      // lane 4j+3 holds full e[t]
            ex = fexp(acc + bvd0);          // valid at lanes 4j+3
        }

        // phase f: ctx partial (lane=m) from own-wave ex; publish 2 scalars
        {
            float p0 = 0.0f, p1 = 0.0f, p2 = 0.0f, p3 = 0.0f;
            #pragma unroll
            for (int j = 0; j < 4; j++) {
                p0 = fmaf(rdlane(ex, 4 * j + 3),        enc_r[j],      p0);
                p1 = fmaf(rdlane(ex, 4 * (j + 4) + 3),  enc_r[4 + j],  p1);
                p2 = fmaf(rdlane(ex, 4 * (j + 8) + 3),  enc_r[8 + j],  p2);
                p3 = fmaf(rdlane(ex, 4 * (j + 12) + 3), enc_r[12 + j], p3);
            }
            float ctxpart = (p0 + p1) + (p2 + p3);      // UNscaled
            if (st == Tn - 2) ctxp[wv * 64 + lane] = ctxpart;
            f32x2 w2;
            w2.x = ctxpart * Wde;
            w2.y = ((lane & 3) == 3) ? ex : 0.0f;       // denom contribution
            w2.x += dppmov<0x111>(w2.x); w2.y += dppmov<0x111>(w2.y);
            w2.x += dppmov<0x112>(w2.x); w2.y += dppmov<0x112>(w2.y);
            w2.x += dppmov<0x114>(w2.x); w2.y += dppmov<0x114>(w2.y);
            w2.x += dppmov<0x118>(w2.x); w2.y += dppmov<0x118>(w2.y);
            w2.x += dppmov<0x142>(w2.x); w2.y += dppmov<0x142>(w2.y);
            w2.x += dppmov<0x143>(w2.x); w2.y += dppmov<0x143>(w2.y);
            if (lane == 63) ysden[nxt * NW + wv] = w2;
        }
        __syncthreads();  // B2: ysden (and last-step ctxp) ready
    }

    // ---- epilogue: out[b][p] = ((concat(h,ctx) @ Wvb + bvb) * Wb[p]) + bWb[p]
    //      last step (st=126, par=0) wrote ysden[1][*]; ctxp holds unscaled.
    if (wv == 0) {
        float dtot = 0.0f;
        #pragma unroll
        for (int w = 0; w < NW; w++) dtot += ysden[NW + w].y;
        float invS = frcp(dtot);
        float ctxm = 0.0f;
        #pragma unroll
        for (int w = 0; w < NW; w++) ctxm += ctxp[w * 64 + lane];
        ctxm *= invS;
        float part = h * Wvb[lane] + ctxm * Wvb[64 + lane];
        float v = rdlane(wavesum63(part), 63) + bvb[0];
        out[(size_t)b * Pn + lane] = fmaf(v, Wb[lane], bWb[lane]);
    }
}

extern "C" void kernel_launch(void* const* d_in, const int* in_sizes, int n_in,
                              void* d_out, int out_size, void* d_ws, size_t ws_size,
                              hipStream_t stream) {
    const float* data    = (const float*)d_in[0];
    const float* enc     = (const float*)d_in[1];
    const float* h0      = (const float*)d_in[2];
    const float* s0      = (const float*)d_in[3];
    const float* W_dense = (const float*)d_in[4];
    const float* b_dense = (const float*)d_in[5];
    const float* Wk      = (const float*)d_in[6];
    const float* Uk      = (const float*)d_in[7];
    const float* bk      = (const float*)d_in[8];
    const float* Wd      = (const float*)d_in[9];
    const float* bWd     = (const float*)d_in[10];
    const float* Ud      = (const float*)d_in[11];
    const float* bUd     = (const float*)d_in[12];
    const float* vd      = (const float*)d_in[13];
    const float* bvd     = (const float*)d_in[14];
    const float* Wvb     = (const float*)d_in[15];
    const float* bvb     = (const float*)d_in[16];
    const float* Wb      = (const float*)d_in[17];
    const float* bWb     = (const float*)d_in[18];

    decoder_kernel<<<Bn, NTH, SMEM_FLOATS * sizeof(float), stream>>>(
        data, enc, h0, s0, W_dense, b_dense, Wk, Uk, bk,
        Wd, bWd, Ud, bUd, vd, bvd, Wvb, bvb, Wb, bWb, (float*)d_out);
}

// Round 11
// 253.676 us; speedup vs baseline: 1.1634x; 1.1183x over previous
//
#include <hip/hip_runtime.h>

// Decoder scan: B=256 batch, T=128, M=64, P=64, 127 sequential steps.
// One block per batch element (256 blocks = 256 CUs), 512 threads (8 waves,
// 2/SIMD). TWO barriers per step, dproj DISTRIBUTED (16 k's per wave).
// This revision removes per-step work algebraically:
//  - exp-product: tanh(dproj+Ue) = 1 - 2/(1 + D[m]*E[t][m]) with
//    E = exp2(K2*Ue) precomputed (loop-invariant registers) and
//    D = exp2(K2*dproj) computed once per step in phase d. Halves the
//    trans-op count of phase e (no per-element exp2 left).
//  - ew-trick: y needs only ctx.W_dense[1:] = sum_t beta_t * ew[t] where
//    ew[t] = enc[t].W_dense[1:] is loop-invariant. Phase f publishes
//    (sum ex*ew, sum ex) only; the 64-wide ctx is materialized just once
//    at the last step (from LDS).
// Softmax division deferred to next step's phase a.

#define Bn 256
#define Tn 128
#define Mn 64
#define Pn 64
#define NTH 512
#define NW 8
#define UST 68    // padded stride (floats) for enc_s / Ud_s
#define DPST 72   // stride for dpart rows / wave-private D copies
#define K2C 2.885390081777927f  // 2 * log2(e)

typedef float f32x2 __attribute__((ext_vector_type(2)));

__device__ __forceinline__ float fexp(float x) {   // e^x
    return __builtin_amdgcn_exp2f(x * 1.44269504088896341f);
}
__device__ __forceinline__ float fexp2(float x) { return __builtin_amdgcn_exp2f(x); }
__device__ __forceinline__ float frcp(float x) { return __builtin_amdgcn_rcpf(x); }
__device__ __forceinline__ float fsig(float x) { return frcp(1.0f + fexp(-x)); }
__device__ __forceinline__ float ftanh(float x) { return 1.0f - 2.0f * frcp(1.0f + fexp(2.0f * x)); }

template <int CTRL>
__device__ __forceinline__ float dppmov(float x) {
    // invalid source lanes contribute old=0 (safe for additive reductions)
    return __int_as_float(__builtin_amdgcn_update_dpp(
        0, __float_as_int(x), CTRL, 0xf, 0xf, false));
}
__device__ __forceinline__ float rdlane(float x, int l) {
    return __int_as_float(__builtin_amdgcn_readlane(__float_as_int(x), l));
}
// 64-lane sum; total lands in lane 63 (NOT broadcast)
__device__ __forceinline__ float wavesum63(float x) {
    x += dppmov<0x111>(x);  // row_shr:1
    x += dppmov<0x112>(x);  // row_shr:2
    x += dppmov<0x114>(x);  // row_shr:4
    x += dppmov<0x118>(x);  // row_shr:8
    x += dppmov<0x142>(x);  // row_bcast:15
    x += dppmov<0x143>(x);  // row_bcast:31
    return x;
}

// LDS layout (floats):
#define OFF_ENC   0        // 128*68 = 8704 (staging + last-step ctx)
#define OFF_UD    8704     // 64*68  = 4352 (init only)
#define OFF_PRE   13056    // 256 (init only)
#define OFF_DPART 13312    // 8*72 = 576 (shared dproj partials)
#define OFF_DPW   13888    // 8*72 = 576 (wave-private D = exp2(K2*dproj))
#define OFF_YSDEN 14464    // f32x2[2][8] = 32 floats (8B aligned)
#define OFF_CTXP  14496    // 512
#define SMEM_FLOATS 15008  // 60.0 KB

__global__ __launch_bounds__(NTH, 2)
void decoder_kernel(const float* __restrict__ data, const float* __restrict__ enc,
                    const float* __restrict__ h0, const float* __restrict__ s0,
                    const float* __restrict__ W_dense, const float* __restrict__ b_dense,
                    const float* __restrict__ Wk, const float* __restrict__ Uk,
                    const float* __restrict__ bk,
                    const float* __restrict__ Wd, const float* __restrict__ bWd,
                    const float* __restrict__ Ud, const float* __restrict__ bUd,
                    const float* __restrict__ vd, const float* __restrict__ bvd,
                    const float* __restrict__ Wvb, const float* __restrict__ bvb,
                    const float* __restrict__ Wb, const float* __restrict__ bWb,
                    float* __restrict__ out)
{
    extern __shared__ float smem[];
    float* enc_s  = smem + OFF_ENC;
    float* Ud_s   = smem + OFF_UD;
    float* pre_s  = smem + OFF_PRE;
    float* dpart  = smem + OFF_DPART;
    float* dprojw = smem + OFF_DPW;
    f32x2* ysden  = (f32x2*)(smem + OFF_YSDEN);
    float* ctxp   = smem + OFF_CTXP;

    const int b    = blockIdx.x;
    const int tid  = threadIdx.x;
    const int lane = tid & 63;
    const int wv   = tid >> 6;          // 0..7

    // ---- init: stage enc (stride 68), Ud (stride 68); pre = h0@Uk+bk ----
    {
        const float* encg = enc + (size_t)b * Tn * Mn;
        #pragma unroll
        for (int i = 0; i < 4; i++) {
            int flat = (i * NTH + tid) * 4;          // 0..8188
            int t = flat >> 6, m = flat & 63;
            *(float4*)(enc_s + t * UST + m) = *(const float4*)(encg + flat);
        }
        #pragma unroll
        for (int i = 0; i < 2; i++) {
            int flat = (i * NTH + tid) * 4;          // 0..4092
            int k = flat >> 6, n = flat & 63;
            *(float4*)(Ud_s + k * UST + n) = *(const float4*)(Ud + flat);
        }
        if (tid < 4 * Pn) {
            float s = bk[tid];
            const float* h0b = h0 + b * Pn;
            #pragma unroll
            for (int k = 0; k < Pn; k++) s = fmaf(h0b[k], Uk[k * 4 * Pn + tid], s);
            pre_s[tid] = s;
        }
        if (tid < 2 * NW) {                          // both parities
            f32x2 z; z.x = 0.0f; z.y = 0.125f;       // den sums to 1 -> ctx=0
            ysden[tid] = z;
        }
    }
    __syncthreads();

    // ---- E slice in registers: E = exp2(K2*(enc[t] @ Ud[:, m0..15] + bUd))
    //      t = 16*wv + (lane>>2), q = lane&3, m0 = 16q
    const int t_e = 16 * wv + (lane >> 2), q_e = lane & 3, m0 = q_e * 16;
    f32x2 ue_e2[8];
    {
        float acc[16];
        #pragma unroll
        for (int j = 0; j < 16; j++) acc[j] = bUd[m0 + j];
        for (int k = 0; k < Mn; k++) {
            float a = enc_s[t_e * UST + k];
            const float4* ud = (const float4*)(Ud_s + k * UST + m0);
            #pragma unroll
            for (int j4 = 0; j4 < 4; j4++) {
                float4 u = ud[j4];
                acc[4 * j4 + 0] = fmaf(a, u.x, acc[4 * j4 + 0]);
                acc[4 * j4 + 1] = fmaf(a, u.y, acc[4 * j4 + 1]);
                acc[4 * j4 + 2] = fmaf(a, u.z, acc[4 * j4 + 2]);
                acc[4 * j4 + 3] = fmaf(a, u.w, acc[4 * j4 + 3]);
            }
        }
        #pragma unroll
        for (int j = 0; j < 8; j++) {
            ue_e2[j].x = fexp2(K2C * acc[2 * j]);
            ue_e2[j].y = fexp2(K2C * acc[2 * j + 1]);
        }
    }

    // ---- per-lane loop-invariant registers ----
    float wd_r[16];                                    // wave's 16 Wd rows (K2-scaled)
    #pragma unroll
    for (int j = 0; j < 16; j++)
        wd_r[j] = K2C * Wd[(16 * wv + j) * Mn + lane];
    const float W0  = W_dense[0];
    const float bd  = b_dense[0];
    const float wk_i = Wk[lane], wk_f = Wk[64 + lane],
                wk_g = Wk[128 + lane], wk_o = Wk[192 + lane];
    const float s0v   = s0[b * Pn + lane];
    const float bvd0  = bvd[0];
    const float bwd_l = K2C * bWd[lane];
    f32x2 vd2[8];
    float sumvd16 = 0.0f;
    #pragma unroll
    for (int j = 0; j < 8; j++) {
        float va = vd[m0 + 2 * j], vb = vd[m0 + 2 * j + 1];
        vd2[j].x = -2.0f * va; vd2[j].y = -2.0f * vb;
        sumvd16 += va + vb;
    }
    // ew[t_e] = enc[t_e,:] . W_dense[1:]  (loop-invariant scalar per thread)
    float ewt = 0.0f;
    {
        const float* er = enc_s + t_e * UST;
        #pragma unroll
        for (int m = 0; m < Mn; m++) ewt = fmaf(er[m], W_dense[1 + m], ewt);
    }
    const float pre_i = pre_s[lane];
    const float pre_f = pre_s[64 + lane];
    const float pre_g = pre_s[128 + lane];
    const float pre_o = pre_s[192 + lane];
    const bool hv_sel = (wv < 4);
    const int  base16 = (wv & 3) * 16;
    // x row in registers (broadcast later via v_readlane)
    const float* xb = data + (size_t)b * (Tn - 1);
    const float x_lo = xb[lane];                           // 0..63
    const float x_hi = (lane < 63) ? xb[64 + lane] : 0.0f; // 64..126

    float h = 0.0f, c = 0.0f;
    float* dp_my = dprojw + wv * DPST;                 // wave-private D values

    for (int st = 0; st < Tn - 1; ++st) {
        const int par = st & 1, nxt = par ^ 1;

        // phase a: y = x[st]*W0 + (sum_w num)/(sum_w den) + bd
        f32x2 yv = ysden[par * NW + (lane & 7)];
        yv.x += dppmov<0x111>(yv.x); yv.y += dppmov<0x111>(yv.y);
        yv.x += dppmov<0x112>(yv.x); yv.y += dppmov<0x112>(yv.y);
        yv.x += dppmov<0x114>(yv.x); yv.y += dppmov<0x114>(yv.y);
        float ytot = rdlane(yv.x, 7);
        float dtot = rdlane(yv.y, 7);
        float xs = (st < 64) ? rdlane(x_lo, st) : rdlane(x_hi, st - 64);
        float y = fmaf(xs, W0, fmaf(ytot, frcp(dtot), bd));

        // phase b: LSTM gates (state resets to h0,s0; pre = h0@Uk+bk)
        float zi = fmaf(y, wk_i, pre_i);
        float zf = fmaf(y, wk_f, pre_f);
        float zg = fmaf(y, wk_g, pre_g);
        float zo = fmaf(y, wk_o, pre_o);
        c = fsig(zf) * s0v + fsig(zi) * ftanh(zg);
        h = fsig(zo) * ftanh(c);

        // phase c: dpart[wv][m] = sum_{j<16} hc[16wv+j] * K2*Wd[16wv+j][m]
        {
            float hv = hv_sel ? h : c;
            float p0 = 0.0f, p1 = 0.0f, p2 = 0.0f, p3 = 0.0f;
            #pragma unroll
            for (int j = 0; j < 4; j++) {
                p0 = fmaf(rdlane(hv, base16 + j),      wd_r[j],      p0);
                p1 = fmaf(rdlane(hv, base16 + 4 + j),  wd_r[4 + j],  p1);
                p2 = fmaf(rdlane(hv, base16 + 8 + j),  wd_r[8 + j],  p2);
                p3 = fmaf(rdlane(hv, base16 + 12 + j), wd_r[12 + j], p3);
            }
            dpart[wv * DPST + lane] = (p0 + p1) + (p2 + p3);
        }
        __syncthreads();  // B1: dpart ready

        // phase d: every wave (redundantly) reduces 8 partials and applies
        // exp2 -> wave-private D[m] = exp2(K2*(dproj[m]+bWd[m]))
        {
            float v0 = dpart[0 * DPST + lane] + dpart[1 * DPST + lane];
            float v1 = dpart[2 * DPST + lane] + dpart[3 * DPST + lane];
            float v2 = dpart[4 * DPST + lane] + dpart[5 * DPST + lane];
            float v3 = dpart[6 * DPST + lane] + dpart[7 * DPST + lane];
            dp_my[lane] = fexp2(((v0 + v1) + (v2 + v3)) + bwd_l);
        }
        // in-wave LDS RAW below (compiler inserts lgkmcnt waits).

        // phase e: e[t] = sumvd - 2*sum_m vd/(1 + E*D); ex=exp(e) @ lanes 4j+3
        float ex;
        {
            float4 d[4];
            const float4* dp4 = (const float4*)(dp_my + m0);
            #pragma unroll
            for (int i = 0; i < 4; i++) d[i] = dp4[i];
            f32x2 accA; accA.x = sumvd16; accA.y = 0.0f;
            f32x2 accB; accB.x = 0.0f;    accB.y = 0.0f;
            #pragma unroll
            for (int i = 0; i < 4; i++) {
                f32x2 eA = ue_e2[2 * i], eB = ue_e2[2 * i + 1];
                f32x2 rA, rB;
                rA.x = frcp(fmaf(eA.x, d[i].x, 1.0f));
                rA.y = frcp(fmaf(eA.y, d[i].y, 1.0f));
                accA += vd2[2 * i] * rA;
                rB.x = frcp(fmaf(eB.x, d[i].z, 1.0f));
                rB.y = frcp(fmaf(eB.y, d[i].w, 1.0f));
                accB += vd2[2 * i + 1] * rB;
            }
            f32x2 accT = accA + accB;
            float acc = accT.x + accT.y;
            acc += dppmov<0x111>(acc);
            acc += dppmov<0x112>(acc);      // lane 4j+3 holds full e[t]
            ex = fexp(acc + bvd0);          // valid at lanes 4j+3
        }

        // phase f: publish 2 scalars (num = sum ex*ew, den = sum ex)
        {
            const bool own = ((lane & 3) == 3);
            f32x2 w2;
            w2.x = own ? ex * ewt : 0.0f;
            w2.y = own ? ex : 0.0f;
            w2.x += dppmov<0x111>(w2.x); w2.y += dppmov<0x111>(w2.y);
            w2.x += dppmov<0x112>(w2.x); w2.y += dppmov<0x112>(w2.y);
            w2.x += dppmov<0x114>(w2.x); w2.y += dppmov<0x114>(w2.y);
            w2.x += dppmov<0x118>(w2.x); w2.y += dppmov<0x118>(w2.y);
            w2.x += dppmov<0x142>(w2.x); w2.y += dppmov<0x142>(w2.y);
            w2.x += dppmov<0x143>(w2.x); w2.y += dppmov<0x143>(w2.y);
            if (lane == 63) ysden[nxt * NW + wv] = w2;
            if (st == Tn - 2) {             // materialize ctx once (unscaled)
                float p = 0.0f;
                #pragma unroll
                for (int j = 0; j < 16; j++)
                    p = fmaf(rdlane(ex, 4 * j + 3),
                             enc_s[(16 * wv + j) * UST + lane], p);
                ctxp[wv * 64 + lane] = p;
            }
        }
        __syncthreads();  // B2: ysden (and last-step ctxp) ready
    }

    // ---- epilogue: out[b][p] = ((concat(h,ctx) @ Wvb + bvb) * Wb[p]) + bWb[p]
    //      last step (st=126, par=0) wrote ysden[1][*]; ctxp holds unscaled.
    if (wv == 0) {
        float dtot = 0.0f;
        #pragma unroll
        for (int w = 0; w < NW; w++) dtot += ysden[NW + w].y;
        float invS = frcp(dtot);
        float ctxm = 0.0f;
        #pragma unroll
        for (int w = 0; w < NW; w++) ctxm += ctxp[w * 64 + lane];
        ctxm *= invS;
        float part = h * Wvb[lane] + ctxm * Wvb[64 + lane];
        float v = rdlane(wavesum63(part), 63) + bvb[0];
        out[(size_t)b * Pn + lane] = fmaf(v, Wb[lane], bWb[lane]);
    }
}

extern "C" void kernel_launch(void* const* d_in, const int* in_sizes, int n_in,
                              void* d_out, int out_size, void* d_ws, size_t ws_size,
                              hipStream_t stream) {
    const float* data    = (const float*)d_in[0];
    const float* enc     = (const float*)d_in[1];
    const float* h0      = (const float*)d_in[2];
    const float* s0      = (const float*)d_in[3];
    const float* W_dense = (const float*)d_in[4];
    const float* b_dense = (const float*)d_in[5];
    const float* Wk      = (const float*)d_in[6];
    const float* Uk      = (const float*)d_in[7];
    const float* bk      = (const float*)d_in[8];
    const float* Wd      = (const float*)d_in[9];
    const float* bWd     = (const float*)d_in[10];
    const float* Ud      = (const float*)d_in[11];
    const float* bUd     = (const float*)d_in[12];
    const float* vd      = (const float*)d_in[13];
    const float* bvd     = (const float*)d_in[14];
    const float* Wvb     = (const float*)d_in[15];
    const float* bvb     = (const float*)d_in[16];
    const float* Wb      = (const float*)d_in[17];
    const float* bWb     = (const float*)d_in[18];

    decoder_kernel<<<Bn, NTH, SMEM_FLOATS * sizeof(float), stream>>>(
        data, enc, h0, s0, W_dense, b_dense, Wk, Uk, bk,
        Wd, bWd, Ud, bUd, vd, bvd, Wvb, bvb, Wb, bWb, (float*)d_out);
}